// Round 1
// baseline (179.696 us; speedup 1.0000x reference)
//
#include <hip/hip_runtime.h>

#define HDIM 256   // output hidden dim
#define KDIM 512   // 2*HDIM (concat)
#define ROWS 16    // batch rows per block
#define LN_EPS 1e-5f

// Kernel A: copy hidden2 -> out table region; init winner slots for touched nodes.
__global__ __launch_bounds__(256) void copy_init_kernel(
    const float4* __restrict__ src, float4* __restrict__ dst,
    int* __restrict__ winner, const int* __restrict__ node_batch,
    int n4, int B)
{
    int tid = blockIdx.x * blockDim.x + threadIdx.x;
    int stride = gridDim.x * blockDim.x;
    for (int i = tid; i < n4; i += stride) dst[i] = src[i];
    for (int i = tid; i < B; i += stride) winner[node_batch[i]] = -1;
}

// Kernel B: last-occurrence-wins via atomicMax over batch index.
__global__ __launch_bounds__(256) void winner_kernel(
    int* __restrict__ winner, const int* __restrict__ node_batch, int B)
{
    int i = blockIdx.x * blockDim.x + threadIdx.x;
    if (i < B) atomicMax(&winner[node_batch[i]], i);
}

// Kernel C: gather+mean -> concat -> GEMM -> bias+ReLU -> LayerNorm -> stores.
// 256 threads = 4 waves. Each block handles ROWS=16 batch rows.
// GEMM thread tile: 4 rows x 4 cols; lane c = t&63 owns cols 4c..4c+3,
// group g = t>>6 owns rows 4g..4g+3 (each row lives entirely in one wave ->
// LayerNorm reduction is a 64-lane shuffle reduce).
__global__ __launch_bounds__(256) void fused_kernel(
    const float* __restrict__ hidden1,
    const float* __restrict__ W2,      // [512][256] row-major
    const float* __restrict__ bias2,   // [256]
    const float* __restrict__ gamma2,  // [256]
    const float* __restrict__ beta2,   // [256]
    const int* __restrict__ node_batch,
    const int* __restrict__ neigh2,
    const int* __restrict__ winner,
    float* __restrict__ out_h2,        // [B][256]
    float* __restrict__ out_tab,       // [N][256]
    int B, int S)
{
    __shared__ float x[ROWS][KDIM];    // 32 KB
    const int t = threadIdx.x;
    const int row0 = blockIdx.x * ROWS;
    const float invS = 1.0f / (float)S;

    // ---- stage 1: gather neighbors (mean) + self row into LDS ----
    // thread t handles feature dim t (coalesced across lanes).
    for (int r = 0; r < ROWS; ++r) {
        int b = row0 + r;
        if (b >= B) b = B - 1;                     // clamp (B%ROWS==0 normally)
        const int* nb = neigh2 + (size_t)b * S;    // wave-uniform scalar loads
        float a = 0.0f;
        for (int s = 0; s < S; ++s)
            a += hidden1[(size_t)nb[s] * HDIM + t];
        x[r][t] = a * invS;                        // agg first (concat order)
        x[r][HDIM + t] = hidden1[(size_t)node_batch[b] * HDIM + t];
    }
    __syncthreads();

    // ---- stage 2: GEMM  h = x @ W2 ----
    const int c = t & 63;      // column group
    const int g = t >> 6;      // row group
    float acc[4][4] = {{0.f,0.f,0.f,0.f},{0.f,0.f,0.f,0.f},
                       {0.f,0.f,0.f,0.f},{0.f,0.f,0.f,0.f}};

    for (int k = 0; k < KDIM; k += 4) {
        // W2 rows k..k+3, 4 consecutive cols per lane -> 4x global dwordx4
        float w[4][4];
        #pragma unroll
        for (int kk = 0; kk < 4; ++kk) {
            float4 tmp = *(const float4*)&W2[(size_t)(k + kk) * HDIM + 4 * c];
            w[kk][0] = tmp.x; w[kk][1] = tmp.y; w[kk][2] = tmp.z; w[kk][3] = tmp.w;
        }
        #pragma unroll
        for (int rr = 0; rr < 4; ++rr) {
            // 16B broadcast read from LDS (uniform addr within wave)
            float4 xv = *(const float4*)&x[4 * g + rr][k];
            float xk[4] = {xv.x, xv.y, xv.z, xv.w};
            #pragma unroll
            for (int kk = 0; kk < 4; ++kk) {
                #pragma unroll
                for (int jj = 0; jj < 4; ++jj)
                    acc[rr][jj] = fmaf(xk[kk], w[kk][jj], acc[rr][jj]);
            }
        }
    }

    // ---- stage 3: bias + ReLU + LayerNorm + stores ----
    float4 bb = *(const float4*)&bias2[4 * c];
    float bbar[4] = {bb.x, bb.y, bb.z, bb.w};
    float4 gg = *(const float4*)&gamma2[4 * c];
    float gar[4] = {gg.x, gg.y, gg.z, gg.w};
    float4 ee = *(const float4*)&beta2[4 * c];
    float ear[4] = {ee.x, ee.y, ee.z, ee.w};

    #pragma unroll
    for (int rr = 0; rr < 4; ++rr) {
        float v[4];
        float s = 0.f, q = 0.f;
        #pragma unroll
        for (int jj = 0; jj < 4; ++jj) {
            float h = fmaxf(acc[rr][jj] + bbar[jj], 0.0f);
            v[jj] = h;
            s += h;
            q += h * h;
        }
        // 64-lane butterfly reduce (row lives in one wave)
        #pragma unroll
        for (int off = 32; off > 0; off >>= 1) {
            s += __shfl_xor(s, off, 64);
            q += __shfl_xor(q, off, 64);
        }
        float mu  = s * (1.0f / (float)HDIM);
        float var = q * (1.0f / (float)HDIM) - mu * mu;
        float rstd = rsqrtf(var + LN_EPS);

        int row = row0 + 4 * g + rr;
        if (row < B) {
            float4 o;
            o.x = gar[0] * (v[0] - mu) * rstd + ear[0];
            o.y = gar[1] * (v[1] - mu) * rstd + ear[1];
            o.z = gar[2] * (v[2] - mu) * rstd + ear[2];
            o.w = gar[3] * (v[3] - mu) * rstd + ear[3];
            *(float4*)&out_h2[(size_t)row * HDIM + 4 * c] = o;
            int node = node_batch[row];
            if (winner[node] == row)
                *(float4*)&out_tab[(size_t)node * HDIM + 4 * c] = o;
        }
    }
}

extern "C" void kernel_launch(void* const* d_in, const int* in_sizes, int n_in,
                              void* d_out, int out_size, void* d_ws, size_t ws_size,
                              hipStream_t stream) {
    // Inputs (setup_inputs order):
    // 0 feats (UNUSED - layer 1 is dead code), 1 hidden1, 2 hidden2,
    // 3 W1 (unused), 4 b1, 5 g1, 6 be1 (unused),
    // 7 W2, 8 b2, 9 g2, 10 be2, 11 node_batch, 12 neigh1 (unused), 13 neigh2
    const float* hidden1 = (const float*)d_in[1];
    const float* hidden2 = (const float*)d_in[2];
    const float* W2      = (const float*)d_in[7];
    const float* b2      = (const float*)d_in[8];
    const float* g2      = (const float*)d_in[9];
    const float* be2     = (const float*)d_in[10];
    const int* node_batch = (const int*)d_in[11];
    const int* neigh2     = (const int*)d_in[13];

    const int B  = in_sizes[11];          // 16384
    const int S  = in_sizes[13] / B;      // 10
    const int NH = in_sizes[2];           // N*256 floats

    float* out_h2  = (float*)d_out;                       // [B,256]
    float* out_tab = out_h2 + (size_t)B * HDIM;           // [N,256]
    int*   winner  = (int*)d_ws;                          // N ints

    hipLaunchKernelGGL(copy_init_kernel, dim3(2048), dim3(256), 0, stream,
                       (const float4*)hidden2, (float4*)out_tab,
                       winner, node_batch, NH / 4, B);
    hipLaunchKernelGGL(winner_kernel, dim3((B + 255) / 256), dim3(256), 0, stream,
                       winner, node_batch, B);
    hipLaunchKernelGGL(fused_kernel, dim3((B + ROWS - 1) / ROWS), dim3(256), 0, stream,
                       hidden1, W2, b2, g2, be2, node_batch, neigh2, winner,
                       out_h2, out_tab, B, S);
}